// Round 1
// baseline (256.323 us; speedup 1.0000x reference)
//
#include <hip/hip_runtime.h>
#include <hip/hip_bf16.h>

#define BATCH 8
#define V 2048
#define H 256
#define D 128

// ---------------- K1: p[b*V+v][d] = sum_h x[row][h] * W[d][h] ----------------
__global__ __launch_bounds__(256) void k_proj(const float* __restrict__ x,
                                              const float* __restrict__ W,
                                              float* __restrict__ p) {
  __shared__ float xs[32 * H];  // 32 rows x 256 h = 32 KB
  const int row0 = blockIdx.x * 32;
  const float4* xsrc = (const float4*)(x + (size_t)row0 * H);
  float4* xdst = (float4*)xs;
#pragma unroll
  for (int t = 0; t < 8; ++t) xdst[threadIdx.x + 256 * t] = xsrc[threadIdx.x + 256 * t];
  __syncthreads();

  const int d = threadIdx.x & 127;
  const int rg = threadIdx.x >> 7;  // 0/1: rows rg, rg+2, ..., rg+30
  float acc[16];
#pragma unroll
  for (int k = 0; k < 16; ++k) acc[k] = 0.f;

  const float4* wrow = (const float4*)(W + (size_t)d * H);
  for (int h4 = 0; h4 < H / 4; ++h4) {
    const float4 wv = wrow[h4];
#pragma unroll
    for (int k = 0; k < 16; ++k) {
      const float4 xv = *(const float4*)(xs + (rg + 2 * k) * H + h4 * 4);
      acc[k] += wv.x * xv.x + wv.y * xv.y + wv.z * xv.z + wv.w * xv.w;
    }
  }
#pragma unroll
  for (int k = 0; k < 16; ++k)
    p[(size_t)(row0 + rg + 2 * k) * D + d] = acc[k];
}

// ---------------- K2: e_i = p . a[0:128], e_j = p . a[128:256] ----------------
__global__ __launch_bounds__(256) void k_e(const float* __restrict__ p,
                                           const float* __restrict__ a,
                                           float* __restrict__ ei,
                                           float* __restrict__ ej) {
  const int row = blockIdx.x * 4 + (threadIdx.x >> 6);
  const int lane = threadIdx.x & 63;
  const float* pr = p + (size_t)row * D;
  const float p0 = pr[lane], p1 = pr[lane + 64];
  float si = p0 * a[lane] + p1 * a[lane + 64];
  float sj = p0 * a[D + lane] + p1 * a[D + lane + 64];
#pragma unroll
  for (int off = 32; off > 0; off >>= 1) {
    si += __shfl_down(si, off, 64);
    sj += __shfl_down(sj, off, 64);
  }
  if (lane == 0) { ei[row] = si; ej[row] = sj; }
}

// ---------------- K3: inv[b,i] = 1 / sum_j exp(lrelu(e_i+e_j)) * adj[i,j] ----------------
__global__ __launch_bounds__(256) void k_rowsum(const float* __restrict__ ei,
                                                const float* __restrict__ ej,
                                                const int* __restrict__ adj,
                                                float* __restrict__ inv) {
  const int b = blockIdx.x >> 11;       // 2048 rows per batch
  const int i = blockIdx.x & (V - 1);
  const float eiv = ei[blockIdx.x];
  const float* ejb = ej + (size_t)b * V;
  const int* arow = adj + (size_t)i * V;
  float s = 0.f;
  for (int j = threadIdx.x; j < V; j += 256) {
    float sc = eiv + ejb[j];
    sc = sc >= 0.f ? sc : 0.2f * sc;
    s += arow[j] ? __expf(sc) : 0.f;
  }
#pragma unroll
  for (int off = 32; off > 0; off >>= 1) s += __shfl_down(s, off, 64);
  __shared__ float red[4];
  if ((threadIdx.x & 63) == 0) red[threadIdx.x >> 6] = s;
  __syncthreads();
  if (threadIdx.x == 0) inv[blockIdx.x] = 1.f / (red[0] + red[1] + red[2] + red[3]);
}

// ---------------- K4: out[b,i,d] = relu(inv_i * sum_j w_ij * p[b,j,d]) ----------------
// block: 32 i-rows x 128 d; j processed in chunks of 64 staged in LDS.
__global__ __launch_bounds__(256) void k_attn(const float* __restrict__ p,
                                              const float* __restrict__ ei,
                                              const float* __restrict__ ej,
                                              const float* __restrict__ inv,
                                              const int* __restrict__ adj,
                                              float* __restrict__ out) {
  __shared__ float p_lds[64 * D];   // 32 KB: 64 j-rows x 128 d
  __shared__ float w_lds[32 * 64];  // 8 KB:  32 i-rows x 64 j
  const int b = blockIdx.x >> 6;            // 64 blocks per batch
  const int i0 = (blockIdx.x & 63) * 32;
  const size_t pbase = (size_t)b * V * D;

  // mapping for the w-compute phase: thread = (j=0..63, g=0..3), i = g+4k
  const int wj = threadIdx.x & 63;
  const int wg = threadIdx.x >> 6;
  float eiv[8];
#pragma unroll
  for (int k = 0; k < 8; ++k) eiv[k] = ei[(size_t)b * V + i0 + wg + 4 * k];

  // mapping for the accumulate phase: thread = (dq=0..31 -> d=4dq, ig=0..7 -> rows ig*4+r)
  const int dq = threadIdx.x & 31;
  const int ig = threadIdx.x >> 5;
  float4 acc[4];
#pragma unroll
  for (int r = 0; r < 4; ++r) acc[r] = make_float4(0.f, 0.f, 0.f, 0.f);

  for (int c = 0; c < V / 64; ++c) {
    const int jb = c * 64;
    __syncthreads();  // protect prior chunk's reads before overwrite
    // stage p chunk (64 x 128 fp32), coalesced float4
    const float4* psrc = (const float4*)(p + pbase + (size_t)jb * D);
    float4* pdst = (float4*)p_lds;
#pragma unroll
    for (int t = 0; t < 8; ++t) pdst[threadIdx.x + 256 * t] = psrc[threadIdx.x + 256 * t];
    // compute w tile (32 x 64)
    const float ejv = ej[(size_t)b * V + jb + wj];
#pragma unroll
    for (int k = 0; k < 8; ++k) {
      const int i = wg + 4 * k;
      float sc = eiv[k] + ejv;
      sc = sc >= 0.f ? sc : 0.2f * sc;
      const int av = adj[(size_t)(i0 + i) * V + jb + wj];
      w_lds[i * 64 + wj] = av ? __expf(sc) : 0.f;
    }
    __syncthreads();
    // accumulate: per thread a 4(i) x 4(d) register tile, float4 LDS reads both sides
#pragma unroll 4
    for (int jj4 = 0; jj4 < 16; ++jj4) {
      const float4 pv0 = *(const float4*)(p_lds + (jj4 * 4 + 0) * D + dq * 4);
      const float4 pv1 = *(const float4*)(p_lds + (jj4 * 4 + 1) * D + dq * 4);
      const float4 pv2 = *(const float4*)(p_lds + (jj4 * 4 + 2) * D + dq * 4);
      const float4 pv3 = *(const float4*)(p_lds + (jj4 * 4 + 3) * D + dq * 4);
#pragma unroll
      for (int r = 0; r < 4; ++r) {
        const float4 wv = *(const float4*)(w_lds + (ig * 4 + r) * 64 + jj4 * 4);
        acc[r].x += wv.x * pv0.x + wv.y * pv1.x + wv.z * pv2.x + wv.w * pv3.x;
        acc[r].y += wv.x * pv0.y + wv.y * pv1.y + wv.z * pv2.y + wv.w * pv3.y;
        acc[r].z += wv.x * pv0.z + wv.y * pv1.z + wv.z * pv2.z + wv.w * pv3.z;
        acc[r].w += wv.x * pv0.w + wv.y * pv1.w + wv.z * pv2.w + wv.w * pv3.w;
      }
    }
  }
  // epilogue: scale by inv, relu, store
#pragma unroll
  for (int r = 0; r < 4; ++r) {
    const int i = ig * 4 + r;
    const float sc = inv[(size_t)b * V + i0 + i];
    float4 o;
    o.x = fmaxf(acc[r].x * sc, 0.f);
    o.y = fmaxf(acc[r].y * sc, 0.f);
    o.z = fmaxf(acc[r].z * sc, 0.f);
    o.w = fmaxf(acc[r].w * sc, 0.f);
    *(float4*)(out + ((size_t)b * V + i0 + i) * D + dq * 4) = o;
  }
}

extern "C" void kernel_launch(void* const* d_in, const int* in_sizes, int n_in,
                              void* d_out, int out_size, void* d_ws, size_t ws_size,
                              hipStream_t stream) {
  const float* x = (const float*)d_in[0];
  const int* adj = (const int*)d_in[1];
  const float* W = (const float*)d_in[2];
  const float* a = (const float*)d_in[3];
  float* out = (float*)d_out;

  char* ws = (char*)d_ws;
  float* p   = (float*)ws;                            // 16384*128*4 = 8 MB
  float* ei  = (float*)(ws + 8388608);                // 64 KB
  float* ej  = (float*)(ws + 8388608 + 65536);        // 64 KB
  float* inv = (float*)(ws + 8388608 + 131072);       // 64 KB

  k_proj<<<dim3((BATCH * V) / 32), dim3(256), 0, stream>>>(x, W, p);
  k_e<<<dim3((BATCH * V) / 4), dim3(256), 0, stream>>>(p, a, ei, ej);
  k_rowsum<<<dim3(BATCH * V), dim3(256), 0, stream>>>(ei, ej, adj, inv);
  k_attn<<<dim3(BATCH * (V / 32)), dim3(256), 0, stream>>>(p, ei, ej, inv, adj, out);
}

// Round 2
// 96.772 us; speedup vs baseline: 2.6487x; 2.6487x over previous
//
#include <hip/hip_runtime.h>
#include <hip/hip_bf16.h>

#define BATCH 8
#define V 2048
#define H 256
#define D 128

typedef __attribute__((ext_vector_type(8))) short bf16x8;
typedef __attribute__((ext_vector_type(4))) float f32x4;

static __device__ __forceinline__ unsigned short bf16u(float f) {
  __hip_bfloat16 h = __float2bfloat16(f);
  unsigned short u;
  __builtin_memcpy(&u, &h, 2);
  return u;
}

// ---------------- K1: p[b*V+v][d] = sum_h x[row][h] * W[d][h] ----------------
__global__ __launch_bounds__(256) void k_proj(const float* __restrict__ x,
                                              const float* __restrict__ W,
                                              float* __restrict__ p) {
  __shared__ float xs[32 * H];
  const int row0 = blockIdx.x * 32;
  const float4* xsrc = (const float4*)(x + (size_t)row0 * H);
  float4* xdst = (float4*)xs;
#pragma unroll
  for (int t = 0; t < 8; ++t) xdst[threadIdx.x + 256 * t] = xsrc[threadIdx.x + 256 * t];
  __syncthreads();

  const int d = threadIdx.x & 127;
  const int rg = threadIdx.x >> 7;
  float acc[16];
#pragma unroll
  for (int k = 0; k < 16; ++k) acc[k] = 0.f;

  const float4* wrow = (const float4*)(W + (size_t)d * H);
  for (int h4 = 0; h4 < H / 4; ++h4) {
    const float4 wv = wrow[h4];
#pragma unroll
    for (int k = 0; k < 16; ++k) {
      const float4 xv = *(const float4*)(xs + (rg + 2 * k) * H + h4 * 4);
      acc[k] += wv.x * xv.x + wv.y * xv.y + wv.z * xv.z + wv.w * xv.w;
    }
  }
#pragma unroll
  for (int k = 0; k < 16; ++k)
    p[(size_t)(row0 + rg + 2 * k) * D + d] = acc[k];
}

// ---------------- K2: e_i / e_j ----------------
__global__ __launch_bounds__(256) void k_e(const float* __restrict__ p,
                                           const float* __restrict__ a,
                                           float* __restrict__ ei,
                                           float* __restrict__ ej) {
  const int row = blockIdx.x * 4 + (threadIdx.x >> 6);
  const int lane = threadIdx.x & 63;
  const float* pr = p + (size_t)row * D;
  const float p0 = pr[lane], p1 = pr[lane + 64];
  float si = p0 * a[lane] + p1 * a[lane + 64];
  float sj = p0 * a[D + lane] + p1 * a[D + lane + 64];
#pragma unroll
  for (int off = 32; off > 0; off >>= 1) {
    si += __shfl_down(si, off, 64);
    sj += __shfl_down(sj, off, 64);
  }
  if (lane == 0) { ei[row] = si; ej[row] = sj; }
}

// ---------------- K_tr: p fp32 [b][j][d] -> pT bf16 [b][d][j] ----------------
__global__ __launch_bounds__(256) void k_tr(const float* __restrict__ p,
                                            __hip_bfloat16* __restrict__ pT) {
  __shared__ __hip_bfloat16 st[128][136];
  const int b = blockIdx.x >> 4;
  const int j0 = (blockIdx.x & 15) * 128;
  const int t = threadIdx.x;
  {
    const int jr = t >> 1;
    const int dh = (t & 1) * 64;
    const float* src = p + ((size_t)(b * V + j0 + jr)) * D + dh;
#pragma unroll
    for (int q = 0; q < 16; ++q) {
      float4 v = *(const float4*)(src + q * 4);
      st[dh + q * 4 + 0][jr] = __float2bfloat16(v.x);
      st[dh + q * 4 + 1][jr] = __float2bfloat16(v.y);
      st[dh + q * 4 + 2][jr] = __float2bfloat16(v.z);
      st[dh + q * 4 + 3][jr] = __float2bfloat16(v.w);
    }
  }
  __syncthreads();
  {
    const int d = t >> 1;
    const int hf = (t & 1) * 64;
    __hip_bfloat16* dst = pT + ((size_t)b * D + d) * V + j0 + hf;
#pragma unroll
    for (int q = 0; q < 8; ++q)
      *(bf16x8*)(dst + q * 8) = *(const bf16x8*)(&st[d][hf + q * 8]);
  }
}

// ---------------- K_pack: adj int32 -> bitmask words [V][64] ----------------
__global__ __launch_bounds__(256) void k_pack(const int* __restrict__ adj,
                                              unsigned int* __restrict__ pk) {
  const int i = blockIdx.x;
  const int w = threadIdx.x >> 6, lane = threadIdx.x & 63;
  const int* row = adj + (size_t)i * V;
#pragma unroll
  for (int it = 0; it < 8; ++it) {
    const int j = it * 256 + w * 64 + lane;
    unsigned long long m = __ballot(row[j] != 0);
    if (lane < 2)
      pk[i * 64 + it * 8 + w * 2 + lane] = (unsigned int)(m >> (lane * 32));
  }
}

// ---------------- K_attn: MFMA out = relu(inv * (w @ p)) ----------------
// grid: 8 batches x 32 i-tiles(64 rows); block 256 = 4 waves (2M x 2N),
// wave tile 32(i) x 64(d); K(=j) chunks of 64, pT staged in LDS double-buffer.
__global__ __launch_bounds__(256, 1) void k_attn(
    const __hip_bfloat16* __restrict__ pT,
    const float* __restrict__ ei, const float* __restrict__ ej,
    const unsigned int* __restrict__ adjp,
    float* __restrict__ out) {
  __shared__ alignas(16) char lds[32768];  // 2 x (128 d-rows x 64 j bf16)
  const int tid = threadIdx.x;
  const int lane = tid & 63;
  const int wave = tid >> 6;
  const int widm = wave >> 1;
  const int widn = wave & 1;
  const int b = blockIdx.x >> 5;
  const int i0 = (blockIdx.x & 31) * 64;

  const __hip_bfloat16* pTb = pT + (size_t)b * D * V;
  const int iA0 = i0 + widm * 32 + (lane & 15);  // global row, mt=0
  const float eiv0 = ei[b * V + iA0];
  const float eiv1 = ei[b * V + iA0 + 16];
  const float* ejb = ej + b * V;
  const int kq = lane >> 4;  // k-quarter 0..3

  // B-frag LDS byte offsets (XOR-swizzled)
  const int rowb = (widn * 64 + (lane & 15)) * 128;
  const int kb0 = (kq * 16) ^ ((lane & 7) << 4);
  const int kb1 = (64 + kq * 16) ^ ((lane & 7) << 4);

  // staging: wave stages d-rows [wave*32, wave*32+32)
  const int srow = wave * 32 + (lane >> 3);
  const int scol = ((lane & 7) ^ (lane >> 3)) << 3;  // pre-swizzled source col

  f32x4 acc[2][4];
#pragma unroll
  for (int mt = 0; mt < 2; ++mt)
#pragma unroll
    for (int nt = 0; nt < 4; ++nt) acc[mt][nt] = (f32x4){0.f, 0.f, 0.f, 0.f};
  float rsum0 = 0.f, rsum1 = 0.f;

#define STAGE(JB, SEL)                                                          \
  {                                                                             \
    char* base_ = lds + (SEL) * 16384 + wave * 32 * 128;                        \
    _Pragma("unroll") for (int q = 0; q < 4; ++q) {                             \
      const __hip_bfloat16* src_ =                                              \
          pTb + (size_t)(srow + q * 8) * V + (JB) + scol;                       \
      __builtin_amdgcn_global_load_lds(                                         \
          (const __attribute__((address_space(1))) unsigned int*)src_,          \
          (__attribute__((address_space(3))) unsigned int*)(base_ + q * 1024),  \
          16, 0, 0);                                                            \
    }                                                                           \
  }

  STAGE(0, 0)
  STAGE(64, 1)

  // prefetch chunk-0 ej / adj words
  float4 ejf[2][2];
  unsigned int aw[2][2];
  {
    const float* ep = ejb + kq * 8;
    ejf[0][0] = *(const float4*)(ep);
    ejf[0][1] = *(const float4*)(ep + 4);
    ejf[1][0] = *(const float4*)(ep + 32);
    ejf[1][1] = *(const float4*)(ep + 36);
    aw[0][0] = adjp[iA0 * 64 + 0];
    aw[0][1] = adjp[iA0 * 64 + 1];
    aw[1][0] = adjp[(iA0 + 16) * 64 + 0];
    aw[1][1] = adjp[(iA0 + 16) * 64 + 1];
  }
  asm volatile("s_waitcnt vmcnt(0)" ::: "memory");
  __builtin_amdgcn_s_barrier();

  for (int c = 0; c < V / 64; ++c) {
    const int jb = c * 64;
    char* bufc = lds + (c & 1) * 16384;
    // 1. read B frags (current buffer) into regs
    bf16x8 bfr[4][2];
#pragma unroll
    for (int nt = 0; nt < 4; ++nt) {
      bfr[nt][0] = *(const bf16x8*)(bufc + nt * 2048 + rowb + kb0);
      bfr[nt][1] = *(const bf16x8*)(bufc + nt * 2048 + rowb + kb1);
    }
    asm volatile("s_waitcnt lgkmcnt(0)" ::: "memory");
    __builtin_amdgcn_s_barrier();
    // 2. stage chunk c+2 into this buffer (reads done block-wide)
    if (c + 2 < V / 64) STAGE(jb + 128, c & 1)
    // 3. prefetch next chunk's ej/adj
    float4 nejf[2][2];
    unsigned int naw[2][2];
    if (c + 1 < V / 64) {
      const float* ep = ejb + jb + 64 + kq * 8;
      nejf[0][0] = *(const float4*)(ep);
      nejf[0][1] = *(const float4*)(ep + 4);
      nejf[1][0] = *(const float4*)(ep + 32);
      nejf[1][1] = *(const float4*)(ep + 36);
      const int wj = (jb + 64) >> 5;
      naw[0][0] = adjp[iA0 * 64 + wj];
      naw[0][1] = adjp[iA0 * 64 + wj + 1];
      naw[1][0] = adjp[(iA0 + 16) * 64 + wj];
      naw[1][1] = adjp[(iA0 + 16) * 64 + wj + 1];
    }
    // w-gen: compute A fragments in-register (exp weights, masked)
    union { unsigned int u[4]; bf16x8 v; } af[2][2];
#pragma unroll
    for (int mt = 0; mt < 2; ++mt) {
      const float eiv = mt ? eiv1 : eiv0;
#pragma unroll
      for (int ks = 0; ks < 2; ++ks) {
        const unsigned int w = aw[mt][ks];
        float vv[8];
#pragma unroll
        for (int h = 0; h < 2; ++h) {
          const float4 e4 = ejf[ks][h];
#pragma unroll
          for (int e2 = 0; e2 < 4; ++e2) {
            float s = eiv + ((const float*)&e4)[e2];
            s = fmaxf(s, 0.2f * s);
            float xv = __expf(s);
            xv = ((w >> (kq * 8 + h * 4 + e2)) & 1u) ? xv : 0.f;
            vv[h * 4 + e2] = xv;
          }
        }
        const float rs = vv[0] + vv[1] + vv[2] + vv[3] + vv[4] + vv[5] + vv[6] + vv[7];
        if (mt == 0) rsum0 += rs; else rsum1 += rs;
#pragma unroll
        for (int pr = 0; pr < 4; ++pr)
          af[mt][ks].u[pr] = (unsigned int)bf16u(vv[2 * pr]) |
                             ((unsigned int)bf16u(vv[2 * pr + 1]) << 16);
      }
    }
    // 4. MFMA
#pragma unroll
    for (int mt = 0; mt < 2; ++mt)
#pragma unroll
      for (int nt = 0; nt < 4; ++nt)
#pragma unroll
        for (int ks = 0; ks < 2; ++ks)
          acc[mt][nt] = __builtin_amdgcn_mfma_f32_16x16x32_bf16(
              af[mt][ks].v, bfr[nt][ks], acc[mt][nt], 0, 0, 0);
    // 5. drain staging, barrier
    asm volatile("s_waitcnt vmcnt(0)" ::: "memory");
    __builtin_amdgcn_s_barrier();
    // swap prefetch regs (static indices)
#pragma unroll
    for (int a_ = 0; a_ < 2; ++a_)
#pragma unroll
      for (int b_ = 0; b_ < 2; ++b_) {
        ejf[a_][b_] = nejf[a_][b_];
        aw[a_][b_] = naw[a_][b_];
      }
  }

  // epilogue: row denominators via cross-lane reduce, scale, relu, store
  float rt0 = rsum0;
  rt0 += __shfl_xor(rt0, 16, 64);
  rt0 += __shfl_xor(rt0, 32, 64);
  float rt1 = rsum1;
  rt1 += __shfl_xor(rt1, 16, 64);
  rt1 += __shfl_xor(rt1, 32, 64);

  float* ob = out + ((size_t)(b * V + i0 + widm * 32)) * D + widn * 64 + (lane & 15);
#pragma unroll
  for (int mt = 0; mt < 2; ++mt) {
    const float rt = mt ? rt1 : rt0;
#pragma unroll
    for (int r = 0; r < 4; ++r) {
      const int q = kq * 4 + r;  // C/D row within 16-tile: (lane>>4)*4 + reg
      const float inv_ = 1.0f / __shfl(rt, q, 64);
#pragma unroll
      for (int nt = 0; nt < 4; ++nt) {
        const float vql = acc[mt][nt][r] * inv_;
        ob[(size_t)(mt * 16 + q) * D + nt * 16] = fmaxf(vql, 0.f);
      }
    }
  }
}

extern "C" void kernel_launch(void* const* d_in, const int* in_sizes, int n_in,
                              void* d_out, int out_size, void* d_ws, size_t ws_size,
                              hipStream_t stream) {
  const float* x = (const float*)d_in[0];
  const int* adj = (const int*)d_in[1];
  const float* W = (const float*)d_in[2];
  const float* a = (const float*)d_in[3];
  float* out = (float*)d_out;

  char* ws = (char*)d_ws;
  float* p = (float*)ws;                                   // 8 MB
  __hip_bfloat16* pT = (__hip_bfloat16*)(ws + (8u << 20)); // 4 MB
  float* ei = (float*)(ws + (12u << 20));                  // 64 KB
  float* ej = (float*)(ws + (12u << 20) + 65536);          // 64 KB
  unsigned int* adjp = (unsigned int*)(ws + (12u << 20) + 131072);  // 512 KB

  k_pack<<<dim3(V), dim3(256), 0, stream>>>(adj, adjp);
  k_proj<<<dim3((BATCH * V) / 32), dim3(256), 0, stream>>>(x, W, p);
  k_tr<<<dim3(BATCH * (V / 128)), dim3(256), 0, stream>>>(p, pT);
  k_e<<<dim3((BATCH * V) / 4), dim3(256), 0, stream>>>(p, a, ei, ej);
  k_attn<<<dim3(BATCH * (V / 64)), dim3(256), 0, stream>>>(pT, ei, ej, adjp, out);
}

// Round 3
// 68.801 us; speedup vs baseline: 3.7256x; 1.4066x over previous
//
#include <hip/hip_runtime.h>
#include <hip/hip_bf16.h>

#define BATCH 8
#define V 2048
#define H 256
#define D 128

typedef __attribute__((ext_vector_type(8))) short bf16x8;
typedef __attribute__((ext_vector_type(4))) float f32x4;

static __device__ __forceinline__ unsigned short bf16u(float f) {
  __hip_bfloat16 h = __float2bfloat16(f);
  unsigned short u;
  __builtin_memcpy(&u, &h, 2);
  return u;
}

// -------- K_pack: adj -> bitmask words [V][64]; plus W -> Wt (transpose) --------
__global__ __launch_bounds__(256) void k_pack(const int* __restrict__ adj,
                                              const float* __restrict__ W,
                                              unsigned int* __restrict__ pk,
                                              float* __restrict__ Wt) {
  const int blk = blockIdx.x;
  if (blk < V) {
    const int w = threadIdx.x >> 6, lane = threadIdx.x & 63;
    const int* row = adj + (size_t)blk * V;
#pragma unroll
    for (int it = 0; it < 8; ++it) {
      const int j = it * 256 + w * 64 + lane;
      unsigned long long m = __ballot(row[j] != 0);
      if (lane < 2)
        pk[blk * 64 + it * 8 + w * 2 + lane] = (unsigned int)(m >> (lane * 32));
    }
  } else {
    const int d = blk - V;  // 0..127
    Wt[(size_t)threadIdx.x * D + d] = W[(size_t)d * H + threadIdx.x];
  }
}

// -------- K_proj: p = x @ W^T (fp32), fused e_i/e_j + bf16 fragment store --------
// block: 32 j-rows x 128 d; thread = (dq 0..31 -> d=dq*4.., jg 0..7 -> rows jg*4..)
__global__ __launch_bounds__(256, 2) void k_proj(const float* __restrict__ x,
                                                 const float* __restrict__ Wt,
                                                 const float* __restrict__ a,
                                                 __hip_bfloat16* __restrict__ pTf,
                                                 float* __restrict__ ei,
                                                 float* __restrict__ ej) {
  __shared__ float xs[32 * H];            // 32 KB
  __shared__ __hip_bfloat16 st[128][52];  // 13 KB, padded
  const int t = threadIdx.x;
  const int b = blockIdx.x >> 6;
  const int j0 = (blockIdx.x & 63) * 32;
  {
    const float4* xsrc = (const float4*)(x + ((size_t)b * V + j0) * H);
    float4* xdst = (float4*)xs;
#pragma unroll
    for (int q = 0; q < 8; ++q) xdst[t + 256 * q] = xsrc[t + 256 * q];
  }
  __syncthreads();

  const int dq = t & 31;  // d quad: d = dq*4+dd
  const int jg = t >> 5;  // rows jg*4+k
  float acc[4][4];        // [k(row)][dd(col)]
#pragma unroll
  for (int k = 0; k < 4; ++k)
#pragma unroll
    for (int dd = 0; dd < 4; ++dd) acc[k][dd] = 0.f;

  const float* wbase = Wt + dq * 4;
  const float* xbase = xs + jg * 4 * H;
#pragma unroll 2
  for (int h4 = 0; h4 < 64; ++h4) {
    float4 wv[4], xv[4];
#pragma unroll
    for (int hh = 0; hh < 4; ++hh)
      wv[hh] = *(const float4*)(wbase + (size_t)(h4 * 4 + hh) * D);
#pragma unroll
    for (int k = 0; k < 4; ++k)
      xv[k] = *(const float4*)(xbase + k * H + h4 * 4);
#pragma unroll
    for (int k = 0; k < 4; ++k)
#pragma unroll
      for (int dd = 0; dd < 4; ++dd)
        acc[k][dd] += xv[k].x * ((const float*)&wv[0])[dd] +
                      xv[k].y * ((const float*)&wv[1])[dd] +
                      xv[k].z * ((const float*)&wv[2])[dd] +
                      xv[k].w * ((const float*)&wv[3])[dd];
  }

  // e_i / e_j from fp32 accumulators (reduce over dq lanes)
  const float4 aLv = *(const float4*)(a + dq * 4);
  const float4 aRv = *(const float4*)(a + D + dq * 4);
#pragma unroll
  for (int k = 0; k < 4; ++k) {
    float te = acc[k][0] * aLv.x + acc[k][1] * aLv.y + acc[k][2] * aLv.z + acc[k][3] * aLv.w;
    float tf = acc[k][0] * aRv.x + acc[k][1] * aRv.y + acc[k][2] * aRv.z + acc[k][3] * aRv.w;
#pragma unroll
    for (int off = 1; off < 32; off <<= 1) {
      te += __shfl_xor(te, off, 64);
      tf += __shfl_xor(tf, off, 64);
    }
    if (dq == 0) {
      ei[(size_t)b * V + j0 + jg * 4 + k] = te;
      ej[(size_t)b * V + j0 + jg * 4 + k] = tf;
    }
  }

  // bf16 transpose into st: st[d][j_local]
#pragma unroll
  for (int dd = 0; dd < 4; ++dd) {
    union { unsigned short u[4]; unsigned long long ll; } pk_;
#pragma unroll
    for (int k = 0; k < 4; ++k) pk_.u[k] = bf16u(acc[k][dd]);
    *(unsigned long long*)&st[dq * 4 + dd][jg * 4] = pk_.ll;
  }
  __syncthreads();

  // fragment store: pTf[b][c][dt][ks][lane][8]
  const int c = (blockIdx.x & 63) >> 1;
  const int ks = blockIdx.x & 1;
  const int lane = t & 63, g = t >> 6;
#pragma unroll
  for (int ff = 0; ff < 2; ++ff) {
    const int dt = ff * 4 + g;
    const int dR = dt * 16 + (lane & 15);
    const int jc = (lane >> 4) * 8;
    union { unsigned long long ll[2]; bf16x8 v; } vv_;
    vv_.ll[0] = *(const unsigned long long*)&st[dR][jc];
    vv_.ll[1] = *(const unsigned long long*)&st[dR][jc + 4];
    *(bf16x8*)((char*)pTf +
               (((((size_t)b * 32 + c) * 8 + dt) * 2 + ks) * 64 + lane) * 16) = vv_.v;
  }
}

// -------- K_attn: out = relu((w @ p) / rowsum) via MFMA, fragment-native B --------
// grid 512: (b 8) x (dhalf 2) x (ig 32 -> 64 i-rows); 4 waves, wave = 16i x 64d
#define WGEN(AF, EA, EB, AW)                                           \
  {                                                                    \
    float vv[8];                                                       \
    _Pragma("unroll") for (int e_ = 0; e_ < 4; ++e_) {                 \
      float s_ = eiv + ((const float*)&(EA))[e_];                      \
      s_ = fmaxf(s_, 0.2f * s_);                                       \
      float x_ = __expf(s_);                                           \
      vv[e_] = (((AW) >> (kq * 8 + e_)) & 1u) ? x_ : 0.f;              \
    }                                                                  \
    _Pragma("unroll") for (int e_ = 0; e_ < 4; ++e_) {                 \
      float s_ = eiv + ((const float*)&(EB))[e_];                      \
      s_ = fmaxf(s_, 0.2f * s_);                                       \
      float x_ = __expf(s_);                                           \
      vv[4 + e_] = (((AW) >> (kq * 8 + 4 + e_)) & 1u) ? x_ : 0.f;      \
    }                                                                  \
    rsum += ((vv[0] + vv[1]) + (vv[2] + vv[3])) +                      \
            ((vv[4] + vv[5]) + (vv[6] + vv[7]));                       \
    _Pragma("unroll") for (int pr_ = 0; pr_ < 4; ++pr_)                \
      AF.u[pr_] = (unsigned int)bf16u(vv[2 * pr_]) |                   \
                  ((unsigned int)bf16u(vv[2 * pr_ + 1]) << 16);        \
  }

#define STAGE(C, SEL)                                                                \
  {                                                                                  \
    const char* src_ = (const char*)pTf + fb0 + (size_t)(C) * 16384 + wave * 2048 +  \
                       lane * 16;                                                    \
    char* dst_ = lds_ + (SEL) * 8192 + wave * 2048;                                  \
    _Pragma("unroll") for (int q_ = 0; q_ < 2; ++q_) {                               \
      __builtin_amdgcn_global_load_lds(                                              \
          (const __attribute__((address_space(1))) unsigned int*)(src_ + q_ * 1024), \
          (__attribute__((address_space(3))) unsigned int*)(dst_ + q_ * 1024),       \
          16, 0, 0);                                                                 \
    }                                                                                \
  }

__global__ __launch_bounds__(256, 2) void k_attn(
    const __hip_bfloat16* __restrict__ pTf,
    const float* __restrict__ ei, const float* __restrict__ ej,
    const unsigned int* __restrict__ adjp,
    float* __restrict__ out) {
  __shared__ alignas(16) char lds[2][8192];
  char* lds_ = (char*)lds;
  const int t = threadIdx.x, lane = t & 63, wave = t >> 6;
  // bijective XCD chunk swizzle (nwg=512, 64 per XCD)
  const int pay = (blockIdx.x & 7) * 64 + (blockIdx.x >> 3);
  const int bdh = pay >> 5;
  const int ig = pay & 31;
  const int b = bdh >> 1, dh = bdh & 1;
  const int i0 = ig * 64 + wave * 16;
  const int kq = lane >> 4;
  const int iR = i0 + (lane & 15);
  const float eiv = ei[(size_t)b * V + iR];
  const float* ejb = ej + (size_t)b * V;
  const size_t fb0 = ((size_t)b * 32) * 16384 + (size_t)dh * 8192;

  f32x4 acc[4];
#pragma unroll
  for (int nt = 0; nt < 4; ++nt) acc[nt] = (f32x4){0.f, 0.f, 0.f, 0.f};
  float rsum = 0.f;

  STAGE(0, 0)
  STAGE(1, 1)
  float4 e0a, e0b, e1a, e1b;
  unsigned int w0, w1;
  {
    const float* ep = ejb + kq * 8;
    e0a = *(const float4*)ep;
    e0b = *(const float4*)(ep + 4);
    e1a = *(const float4*)(ep + 32);
    e1b = *(const float4*)(ep + 36);
    w0 = adjp[iR * 64];
    w1 = adjp[iR * 64 + 1];
  }
  asm volatile("s_waitcnt vmcnt(8)" ::: "memory");
  __builtin_amdgcn_s_barrier();

  for (int c = 0; c < 32; ++c) {
    const char* buf = lds_ + (c & 1) * 8192;
    bf16x8 bfr[4][2];
#pragma unroll
    for (int nt = 0; nt < 4; ++nt)
#pragma unroll
      for (int ks = 0; ks < 2; ++ks)
        bfr[nt][ks] = *(const bf16x8*)(buf + (nt * 2 + ks) * 1024 + lane * 16);
    asm volatile("s_waitcnt lgkmcnt(0)" ::: "memory");
    __builtin_amdgcn_s_barrier();
    if (c + 2 < 32) STAGE(c + 2, c & 1)
    float4 ne0a, ne0b, ne1a, ne1b;
    unsigned int nw0, nw1;
    if (c + 1 < 32) {
      const float* ep = ejb + (c + 1) * 64 + kq * 8;
      ne0a = *(const float4*)ep;
      ne0b = *(const float4*)(ep + 4);
      ne1a = *(const float4*)(ep + 32);
      ne1b = *(const float4*)(ep + 36);
      nw0 = adjp[iR * 64 + (c + 1) * 2];
      nw1 = adjp[iR * 64 + (c + 1) * 2 + 1];
    }
    union U { unsigned int u[4]; bf16x8 v; } af0, af1;
    WGEN(af0, e0a, e0b, w0)
    WGEN(af1, e1a, e1b, w1)
#pragma unroll
    for (int nt = 0; nt < 4; ++nt) {
      acc[nt] = __builtin_amdgcn_mfma_f32_16x16x32_bf16(af0.v, bfr[nt][0], acc[nt], 0, 0, 0);
      acc[nt] = __builtin_amdgcn_mfma_f32_16x16x32_bf16(af1.v, bfr[nt][1], acc[nt], 0, 0, 0);
    }
    asm volatile("s_waitcnt vmcnt(8)" ::: "memory");
    __builtin_amdgcn_s_barrier();
    e0a = ne0a; e0b = ne0b; e1a = ne1a; e1b = ne1b;
    w0 = nw0; w1 = nw1;
  }

  // epilogue: denominators + scale + relu + store
  float rt = rsum;
  rt += __shfl_xor(rt, 16, 64);
  rt += __shfl_xor(rt, 32, 64);
  float* ob = out + ((size_t)b * V + i0) * D + dh * 64 + (lane & 15);
#pragma unroll
  for (int r = 0; r < 4; ++r) {
    const int q = kq * 4 + r;
    const float inv_ = 1.0f / __shfl(rt, q, 64);
#pragma unroll
    for (int nt = 0; nt < 4; ++nt) {
      const float v = acc[nt][r] * inv_;
      ob[(size_t)q * D + nt * 16] = fmaxf(v, 0.f);
    }
  }
}

extern "C" void kernel_launch(void* const* d_in, const int* in_sizes, int n_in,
                              void* d_out, int out_size, void* d_ws, size_t ws_size,
                              hipStream_t stream) {
  const float* x = (const float*)d_in[0];
  const int* adj = (const int*)d_in[1];
  const float* W = (const float*)d_in[2];
  const float* a = (const float*)d_in[3];
  float* out = (float*)d_out;

  char* ws = (char*)d_ws;
  __hip_bfloat16* pTf = (__hip_bfloat16*)ws;               // 4 MB
  float* ei = (float*)(ws + (4u << 20));                   // 64 KB
  float* ej = (float*)(ws + (4u << 20) + 65536);           // 64 KB
  unsigned int* adjp = (unsigned int*)(ws + (4u << 20) + 131072);  // 512 KB
  float* Wt = (float*)(ws + (4u << 20) + 131072 + 524288); // 128 KB

  k_pack<<<dim3(V + D), dim3(256), 0, stream>>>(adj, W, adjp, Wt);
  k_proj<<<dim3(BATCH * (V / 32)), dim3(256), 0, stream>>>(x, Wt, a, pTf, ei, ej);
  k_attn<<<dim3(BATCH * 2 * (V / 64)), dim3(256), 0, stream>>>(pTf, ei, ej, adjp, out);
}

// Round 4
// 68.759 us; speedup vs baseline: 3.7279x; 1.0006x over previous
//
#include <hip/hip_runtime.h>
#include <hip/hip_bf16.h>

#define BATCH 8
#define V 2048
#define H 256
#define D 128

typedef __attribute__((ext_vector_type(8))) short bf16x8;
typedef __attribute__((ext_vector_type(4))) float f32x4;

static __device__ __forceinline__ unsigned short bf16u(float f) {
  __hip_bfloat16 h = __float2bfloat16(f);
  unsigned short u;
  __builtin_memcpy(&u, &h, 2);
  return u;
}

// -------- K_pack: adj -> bitmask words [V][64]; plus W -> Wt (transpose) --------
__global__ __launch_bounds__(256) void k_pack(const int* __restrict__ adj,
                                              const float* __restrict__ W,
                                              unsigned int* __restrict__ pk,
                                              float* __restrict__ Wt) {
  const int blk = blockIdx.x;
  if (blk < V) {
    const int w = threadIdx.x >> 6, lane = threadIdx.x & 63;
    const int* row = adj + (size_t)blk * V;
#pragma unroll
    for (int it = 0; it < 8; ++it) {
      const int j = it * 256 + w * 64 + lane;
      unsigned long long m = __ballot(row[j] != 0);
      if (lane < 2)
        pk[blk * 64 + it * 8 + w * 2 + lane] = (unsigned int)(m >> (lane * 32));
    }
  } else {
    const int d = blk - V;  // 0..127
    Wt[(size_t)threadIdx.x * D + d] = W[(size_t)d * H + threadIdx.x];
  }
}

// -------- K_proj: p = x @ W^T (fp32), fused e_i + exp-factor tables + bf16 frag store --------
__global__ __launch_bounds__(256, 2) void k_proj(const float* __restrict__ x,
                                                 const float* __restrict__ Wt,
                                                 const float* __restrict__ a,
                                                 __hip_bfloat16* __restrict__ pTf,
                                                 float* __restrict__ ei,
                                                 float* __restrict__ Fj,
                                                 float* __restrict__ Fp) {
  __shared__ float xs[32 * H];            // 32 KB
  __shared__ __hip_bfloat16 st[128][52];  // 13 KB, padded
  const int t = threadIdx.x;
  const int b = blockIdx.x >> 6;
  const int j0 = (blockIdx.x & 63) * 32;
  {
    const float4* xsrc = (const float4*)(x + ((size_t)b * V + j0) * H);
    float4* xdst = (float4*)xs;
#pragma unroll
    for (int q = 0; q < 8; ++q) xdst[t + 256 * q] = xsrc[t + 256 * q];
  }
  __syncthreads();

  const int dq = t & 31;  // d quad: d = dq*4+dd
  const int jg = t >> 5;  // rows jg*4+k
  float acc[4][4];        // [k(row)][dd(col)]
#pragma unroll
  for (int k = 0; k < 4; ++k)
#pragma unroll
    for (int dd = 0; dd < 4; ++dd) acc[k][dd] = 0.f;

  const float* wbase = Wt + dq * 4;
  const float* xbase = xs + jg * 4 * H;
#pragma unroll 2
  for (int h4 = 0; h4 < 64; ++h4) {
    float4 wv[4], xv[4];
#pragma unroll
    for (int hh = 0; hh < 4; ++hh)
      wv[hh] = *(const float4*)(wbase + (size_t)(h4 * 4 + hh) * D);
#pragma unroll
    for (int k = 0; k < 4; ++k)
      xv[k] = *(const float4*)(xbase + k * H + h4 * 4);
#pragma unroll
    for (int k = 0; k < 4; ++k)
#pragma unroll
      for (int dd = 0; dd < 4; ++dd)
        acc[k][dd] += xv[k].x * ((const float*)&wv[0])[dd] +
                      xv[k].y * ((const float*)&wv[1])[dd] +
                      xv[k].z * ((const float*)&wv[2])[dd] +
                      xv[k].w * ((const float*)&wv[3])[dd];
  }

  // e_i / e_j from fp32 accumulators (reduce over dq lanes); store exp-factor tables
  const float4 aLv = *(const float4*)(a + dq * 4);
  const float4 aRv = *(const float4*)(a + D + dq * 4);
#pragma unroll
  for (int k = 0; k < 4; ++k) {
    float te = acc[k][0] * aLv.x + acc[k][1] * aLv.y + acc[k][2] * aLv.z + acc[k][3] * aLv.w;
    float tf = acc[k][0] * aRv.x + acc[k][1] * aRv.y + acc[k][2] * aRv.z + acc[k][3] * aRv.w;
#pragma unroll
    for (int off = 1; off < 32; off <<= 1) {
      te += __shfl_xor(te, off, 64);
      tf += __shfl_xor(tf, off, 64);
    }
    if (dq == 0) {
      const size_t row = (size_t)b * V + j0 + jg * 4 + k;
      ei[row] = te;
      Fj[row] = __expf(tf);
      Fp[row] = __expf(0.2f * tf);
    }
  }

  // bf16 transpose into st: st[d][j_local]
#pragma unroll
  for (int dd = 0; dd < 4; ++dd) {
    union { unsigned short u[4]; unsigned long long ll; } pk_;
#pragma unroll
    for (int k = 0; k < 4; ++k) pk_.u[k] = bf16u(acc[k][dd]);
    *(unsigned long long*)&st[dq * 4 + dd][jg * 4] = pk_.ll;
  }
  __syncthreads();

  // fragment store: pTf[b][c][dt][ks][lane][8]
  const int c = (blockIdx.x & 63) >> 1;
  const int ks = blockIdx.x & 1;
  const int lane = t & 63, g = t >> 6;
#pragma unroll
  for (int ff = 0; ff < 2; ++ff) {
    const int dt = ff * 4 + g;
    const int dR = dt * 16 + (lane & 15);
    const int jc = (lane >> 4) * 8;
    union { unsigned long long ll[2]; bf16x8 v; } vv_;
    vv_.ll[0] = *(const unsigned long long*)&st[dR][jc];
    vv_.ll[1] = *(const unsigned long long*)&st[dR][jc + 4];
    *(bf16x8*)((char*)pTf +
               (((((size_t)b * 32 + c) * 8 + dt) * 2 + ks) * 64 + lane) * 16) = vv_.v;
  }
}

// -------- K_attn: out = relu((w @ p) / rowsum) via MFMA, factorized w-gen --------
// w_ij = adj_ij * (s>=0 ? Ei*Fj : Ei'*F'j), sign test via Fj >= exp(-ei).
#define WGEN(AF, FA, FB, PA, PB, AW)                                   \
  {                                                                    \
    const unsigned int sh_ = (AW) >> kq8;                              \
    float vv[8];                                                       \
    _Pragma("unroll") for (int e_ = 0; e_ < 4; ++e_) {                 \
      const float F_ = ((const float*)&(FA))[e_];                      \
      const float P_ = ((const float*)&(PA))[e_];                      \
      const bool c_ = F_ >= Tth;                                       \
      float w_ = (c_ ? Ei : Eip) * (c_ ? F_ : P_);                     \
      const int m_ = ((int)(sh_ << (31 - e_))) >> 31;                  \
      vv[e_] = __int_as_float(__float_as_int(w_) & m_);                \
    }                                                                  \
    _Pragma("unroll") for (int e_ = 0; e_ < 4; ++e_) {                 \
      const float F_ = ((const float*)&(FB))[e_];                      \
      const float P_ = ((const float*)&(PB))[e_];                      \
      const bool c_ = F_ >= Tth;                                       \
      float w_ = (c_ ? Ei : Eip) * (c_ ? F_ : P_);                     \
      const int m_ = ((int)(sh_ << (27 - e_))) >> 31;                  \
      vv[4 + e_] = __int_as_float(__float_as_int(w_) & m_);            \
    }                                                                  \
    rsum += ((vv[0] + vv[1]) + (vv[2] + vv[3])) +                      \
            ((vv[4] + vv[5]) + (vv[6] + vv[7]));                       \
    _Pragma("unroll") for (int pr_ = 0; pr_ < 4; ++pr_)                \
      AF.u[pr_] = (unsigned int)bf16u(vv[2 * pr_]) |                   \
                  ((unsigned int)bf16u(vv[2 * pr_ + 1]) << 16);        \
  }

#define STAGE(C, SEL)                                                                \
  {                                                                                  \
    const char* src_ = (const char*)pTf + fb0 + (size_t)(C) * 16384 + wave * 2048 +  \
                       lane * 16;                                                    \
    char* dst_ = lds_ + (SEL) * 8192 + wave * 2048;                                  \
    _Pragma("unroll") for (int q_ = 0; q_ < 2; ++q_) {                               \
      __builtin_amdgcn_global_load_lds(                                              \
          (const __attribute__((address_space(1))) unsigned int*)(src_ + q_ * 1024), \
          (__attribute__((address_space(3))) unsigned int*)(dst_ + q_ * 1024),       \
          16, 0, 0);                                                                 \
    }                                                                                \
  }

__global__ __launch_bounds__(256, 2) void k_attn(
    const __hip_bfloat16* __restrict__ pTf,
    const float* __restrict__ ei, const float* __restrict__ Fjt,
    const float* __restrict__ Fpt,
    const unsigned int* __restrict__ adjp,
    float* __restrict__ out) {
  __shared__ alignas(16) char lds[2][8192];
  char* lds_ = (char*)lds;
  const int t = threadIdx.x, lane = t & 63, wave = t >> 6;
  // bijective XCD chunk swizzle (nwg=512, 64 per XCD)
  const int pay = (blockIdx.x & 7) * 64 + (blockIdx.x >> 3);
  const int bdh = pay >> 5;
  const int ig = pay & 31;
  const int b = bdh >> 1, dh = bdh & 1;
  const int i0 = ig * 64 + wave * 16;
  const int kq = lane >> 4;
  const int kq8 = kq * 8;
  const int iR = i0 + (lane & 15);
  const float eiv = ei[(size_t)b * V + iR];
  const float Ei = __expf(eiv);
  const float Eip = __expf(0.2f * eiv);
  const float Tth = __expf(-eiv);
  const float* Fb = Fjt + (size_t)b * V;
  const float* Pb = Fpt + (size_t)b * V;
  const size_t fb0 = ((size_t)b * 32) * 16384 + (size_t)dh * 8192;

  f32x4 acc[4];
#pragma unroll
  for (int nt = 0; nt < 4; ++nt) acc[nt] = (f32x4){0.f, 0.f, 0.f, 0.f};
  float rsum = 0.f;

  STAGE(0, 0)
  STAGE(1, 1)
  float4 f0a, f0b, f1a, f1b, p0a, p0b, p1a, p1b;
  unsigned int w0, w1;
  {
    const float* fp = Fb + kq8;
    const float* pp = Pb + kq8;
    f0a = *(const float4*)fp;       f0b = *(const float4*)(fp + 4);
    f1a = *(const float4*)(fp + 32); f1b = *(const float4*)(fp + 36);
    p0a = *(const float4*)pp;       p0b = *(const float4*)(pp + 4);
    p1a = *(const float4*)(pp + 32); p1b = *(const float4*)(pp + 36);
    w0 = adjp[iR * 64];
    w1 = adjp[iR * 64 + 1];
  }
  asm volatile("s_waitcnt vmcnt(12)" ::: "memory");
  __builtin_amdgcn_s_barrier();

  for (int c = 0; c < 32; ++c) {
    const char* buf = lds_ + (c & 1) * 8192;
    bf16x8 bfr[4][2];
#pragma unroll
    for (int nt = 0; nt < 4; ++nt)
#pragma unroll
      for (int ks = 0; ks < 2; ++ks)
        bfr[nt][ks] = *(const bf16x8*)(buf + (nt * 2 + ks) * 1024 + lane * 16);
    asm volatile("s_waitcnt lgkmcnt(0)" ::: "memory");
    __builtin_amdgcn_s_barrier();
    if (c + 2 < 32) STAGE(c + 2, c & 1)
    float4 nf0a, nf0b, nf1a, nf1b, np0a, np0b, np1a, np1b;
    unsigned int nw0, nw1;
    if (c + 1 < 32) {
      const float* fp = Fb + (c + 1) * 64 + kq8;
      const float* pp = Pb + (c + 1) * 64 + kq8;
      nf0a = *(const float4*)fp;       nf0b = *(const float4*)(fp + 4);
      nf1a = *(const float4*)(fp + 32); nf1b = *(const float4*)(fp + 36);
      np0a = *(const float4*)pp;       np0b = *(const float4*)(pp + 4);
      np1a = *(const float4*)(pp + 32); np1b = *(const float4*)(pp + 36);
      nw0 = adjp[iR * 64 + (c + 1) * 2];
      nw1 = adjp[iR * 64 + (c + 1) * 2 + 1];
    }
    union U { unsigned int u[4]; bf16x8 v; } af0, af1;
    WGEN(af0, f0a, f0b, p0a, p0b, w0)
    WGEN(af1, f1a, f1b, p1a, p1b, w1)
#pragma unroll
    for (int nt = 0; nt < 4; ++nt) {
      acc[nt] = __builtin_amdgcn_mfma_f32_16x16x32_bf16(af0.v, bfr[nt][0], acc[nt], 0, 0, 0);
      acc[nt] = __builtin_amdgcn_mfma_f32_16x16x32_bf16(af1.v, bfr[nt][1], acc[nt], 0, 0, 0);
    }
    asm volatile("s_waitcnt vmcnt(12)" ::: "memory");
    __builtin_amdgcn_s_barrier();
    f0a = nf0a; f0b = nf0b; f1a = nf1a; f1b = nf1b;
    p0a = np0a; p0b = np0b; p1a = np1a; p1b = np1b;
    w0 = nw0; w1 = nw1;
  }

  // epilogue: denominators + scale + relu + store
  float rt = rsum;
  rt += __shfl_xor(rt, 16, 64);
  rt += __shfl_xor(rt, 32, 64);
  float* ob = out + ((size_t)b * V + i0) * D + dh * 64 + (lane & 15);
#pragma unroll
  for (int r = 0; r < 4; ++r) {
    const int q = kq * 4 + r;
    const float inv_ = 1.0f / __shfl(rt, q, 64);
#pragma unroll
    for (int nt = 0; nt < 4; ++nt) {
      const float v = acc[nt][r] * inv_;
      ob[(size_t)q * D + nt * 16] = fmaxf(v, 0.f);
    }
  }
}

extern "C" void kernel_launch(void* const* d_in, const int* in_sizes, int n_in,
                              void* d_out, int out_size, void* d_ws, size_t ws_size,
                              hipStream_t stream) {
  const float* x = (const float*)d_in[0];
  const int* adj = (const int*)d_in[1];
  const float* W = (const float*)d_in[2];
  const float* a = (const float*)d_in[3];
  float* out = (float*)d_out;

  char* ws = (char*)d_ws;
  __hip_bfloat16* pTf = (__hip_bfloat16*)ws;                       // 4 MB
  float* ei = (float*)(ws + (4u << 20));                           // 64 KB
  float* Fj = (float*)(ws + (4u << 20) + 65536);                   // 64 KB
  float* Fp = (float*)(ws + (4u << 20) + 131072);                  // 64 KB
  unsigned int* adjp = (unsigned int*)(ws + (4u << 20) + 196608);  // 512 KB
  float* Wt = (float*)(ws + (4u << 20) + 196608 + 524288);         // 128 KB

  k_pack<<<dim3(V + D), dim3(256), 0, stream>>>(adj, W, adjp, Wt);
  k_proj<<<dim3(BATCH * (V / 32)), dim3(256), 0, stream>>>(x, Wt, a, pTf, ei, Fj, Fp);
  k_attn<<<dim3(BATCH * 2 * (V / 64)), dim3(256), 0, stream>>>(pTf, ei, Fj, Fp, adjp, out);
}